// Round 3
// baseline (878.952 us; speedup 1.0000x reference)
//
#include <hip/hip_runtime.h>
#include <math.h>

// LiftProjectNetwork, CSR-gather formulation (interleaved CSR + shuffle-broadcast gather):
//   build CSR by dst ONCE per call (histogram + scan + fill),
//   then 12 fused layers: g = gather(h, CSR); [normalize g]; out = f([h,g]@W + b)
// N=50000, E=1600000, r=32.

#define R 32
#define EPSN 1e-12f

// ---- CSR build: histogram of dst ----
__global__ void count_kernel(const int* __restrict__ ei, int* __restrict__ counts, int E) {
    int e = blockIdx.x * blockDim.x + threadIdx.x;
    if (e < E) atomicAdd(counts + ei[E + e], 1);
}

// ---- single-block exclusive scan over counts[N] -> offsets[N+1] ----
__global__ void scan_kernel(const int* __restrict__ counts, int* __restrict__ offsets,
                            int* __restrict__ cursor, int N) {
    __shared__ int sums[1024];
    const int tid = threadIdx.x;
    const int chunk = (N + 1023) >> 10;
    const int beg = tid * chunk;
    const int end = min(beg + chunk, N);
    int s = 0;
    for (int i = beg; i < end; ++i) s += counts[i];
    sums[tid] = s;
    __syncthreads();
    for (int off = 1; off < 1024; off <<= 1) {
        int v = (tid >= off) ? sums[tid - off] : 0;
        __syncthreads();
        sums[tid] += v;
        __syncthreads();
    }
    int run = (tid == 0) ? 0 : sums[tid - 1];
    for (int i = beg; i < end; ++i) { offsets[i] = run; cursor[i] = run; run += counts[i]; }
    if (tid == 1023) offsets[N] = sums[1023];
}

// ---- scatter edges into CSR slots, one 8B write per edge ----
__global__ void fill_kernel(const int* __restrict__ ei, const float* __restrict__ ew,
                            int* __restrict__ cursor, int2* __restrict__ csr, int E) {
    int e = blockIdx.x * blockDim.x + threadIdx.x;
    if (e >= E) return;
    int p = atomicAdd(cursor + ei[E + e], 1);
    csr[p] = make_int2(ei[e], __float_as_int(ew[e]));
}

// ---- fused layer: gather + (normalize) + [h,g]@W+b + (normalize|tanh) ----
// block = 256 threads = 8 nodes x 32 lanes; lane j owns feature j.
// Gather: chunks of 32 edges; lane j loads edge beg+j coalesced, shuffle-broadcasts
// (src,w) so 32 independent h-row loads are in flight per chunk.
template <bool LIFT>
__global__ void layer_kernel(const float* __restrict__ h,
                             const int* __restrict__ offsets,
                             const int2* __restrict__ csr,
                             const float* __restrict__ W,  // [64*32] (k, j)
                             const float* __restrict__ b,  // [32]
                             float* __restrict__ out,
                             int N) {
    __shared__ float Ws[64 * R];
    __shared__ float hg[8][64];

    for (int i = threadIdx.x; i < 64 * R; i += blockDim.x) Ws[i] = W[i];

    const int grp  = threadIdx.x >> 5;
    const int j    = threadIdx.x & 31;
    const int node = blockIdx.x * 8 + grp;

    float hv = 0.f, gv = 0.f;
    if (node < N) {
        hv = h[(long long)node * R + j];
        const int beg = offsets[node];
        const int end = offsets[node + 1];
        float g0 = 0.f, g1 = 0.f;
        for (int base = beg; base < end; base += 32) {
            int  e = base + j;
            int  s = 0; float w = 0.f;
            if (e < end) { int2 p = csr[e]; s = p.x; w = __int_as_float(p.y); }
            #pragma unroll
            for (int kk = 0; kk < 4; ++kk) {
                if (base + kk * 8 < end) {   // uniform within the 32-lane group
                    #pragma unroll
                    for (int k8 = 0; k8 < 8; ++k8) {
                        const int k = kk * 8 + k8;
                        int   sk = __shfl(s, k, 32);
                        float wk = __shfl(w, k, 32);
                        float& acc = (k8 & 1) ? g1 : g0;
                        acc = fmaf(h[(long long)sk * R + j], wk, acc);
                    }
                }
            }
        }
        gv = g0 + g1;
    }

    if (LIFT) {
        float s = gv * gv;
        #pragma unroll
        for (int o = 16; o >= 1; o >>= 1) s += __shfl_xor(s, o, 32);
        gv = gv / fmaxf(sqrtf(s), EPSN);
    }

    hg[grp][j]      = hv;
    hg[grp][32 + j] = gv;
    __syncthreads();

    float acc = b[j];
    const float* row = hg[grp];
    #pragma unroll
    for (int k = 0; k < 64; ++k) acc = fmaf(row[k], Ws[k * R + j], acc);

    if (LIFT) {
        float s = acc * acc;
        #pragma unroll
        for (int o = 16; o >= 1; o >>= 1) s += __shfl_xor(s, o, 32);
        acc = acc / fmaxf(sqrtf(s), EPSN);
    } else {
        acc = tanhf(acc);
    }

    if (node < N) out[(long long)node * R + j] = acc;
}

extern "C" void kernel_launch(void* const* d_in, const int* in_sizes, int n_in,
                              void* d_out, int out_size, void* d_ws, size_t ws_size,
                              hipStream_t stream) {
    const float* x      = (const float*)d_in[0];
    const int*   ei     = (const int*)d_in[1];
    const float* ew     = (const float*)d_in[2];
    const float* lift_W = (const float*)d_in[3];
    const float* lift_b = (const float*)d_in[4];
    const float* proj_W = (const float*)d_in[5];
    const float* proj_b = (const float*)d_in[6];

    const int N = in_sizes[0] / R;
    const int E = in_sizes[2];

    // workspace layout
    float* h0      = (float*)d_ws;
    float* h1      = h0 + (size_t)N * R;
    int*   counts  = (int*)(h1 + (size_t)N * R);
    int*   offsets = counts + N;
    int*   cursor  = offsets + N + 1;
    int2*  csr     = (int2*)(cursor + N + 1);   // +1 pad for alignment

    // ---- CSR build (once, reused by all 12 layers) ----
    hipMemsetAsync(counts, 0, (size_t)N * sizeof(int), stream);
    count_kernel<<<(E + 255) / 256, 256, 0, stream>>>(ei, counts, E);
    scan_kernel<<<1, 1024, 0, stream>>>(counts, offsets, cursor, N);
    fill_kernel<<<(E + 255) / 256, 256, 0, stream>>>(ei, ew, cursor, csr, E);

    // ---- 12 fused layers ----
    const float* cur = x;
    float* buf[2] = {h0, h1};
    const int node_blocks = (N + 7) / 8;

    for (int l = 0; l < 12; ++l) {
        const bool lift = (l < 8);
        const float* W = lift ? (lift_W + (size_t)l * 64 * R) : (proj_W + (size_t)(l - 8) * 64 * R);
        const float* b = lift ? (lift_b + (size_t)l * R)      : (proj_b + (size_t)(l - 8) * R);
        float* dst = (l == 11) ? (float*)d_out : buf[l & 1];
        if (lift)
            layer_kernel<true ><<<node_blocks, 256, 0, stream>>>(cur, offsets, csr, W, b, dst, N);
        else
            layer_kernel<false><<<node_blocks, 256, 0, stream>>>(cur, offsets, csr, W, b, dst, N);
        cur = dst;
    }
}

// Round 4
// 856.759 us; speedup vs baseline: 1.0259x; 1.0259x over previous
//
#include <hip/hip_runtime.h>
#include <math.h>

// LiftProjectNetwork, CSR-gather formulation (interleaved CSR + branch-free
// shuffle-broadcast gather):
//   build CSR by dst ONCE per call (histogram + scan + fill),
//   then 12 fused layers: g = gather(h, CSR); [normalize g]; out = f([h,g]@W + b)
// N=50000, E=1600000, r=32.

#define R 32
#define EPSN 1e-12f

// ---- CSR build: histogram of dst ----
__global__ void count_kernel(const int* __restrict__ ei, int* __restrict__ counts, int E) {
    int e = blockIdx.x * blockDim.x + threadIdx.x;
    if (e < E) atomicAdd(counts + ei[E + e], 1);
}

// ---- single-block exclusive scan over counts[N] -> offsets[N+1], also seeds cursor ----
__global__ void scan_kernel(const int* __restrict__ counts, int* __restrict__ offsets,
                            int* __restrict__ cursor, int N) {
    __shared__ int sums[1024];
    const int tid = threadIdx.x;
    const int chunk = (N + 1023) >> 10;
    const int beg = tid * chunk;
    const int end = min(beg + chunk, N);
    int s = 0;
    for (int i = beg; i < end; ++i) s += counts[i];
    sums[tid] = s;
    __syncthreads();
    for (int off = 1; off < 1024; off <<= 1) {
        int v = (tid >= off) ? sums[tid - off] : 0;
        __syncthreads();
        sums[tid] += v;
        __syncthreads();
    }
    int run = (tid == 0) ? 0 : sums[tid - 1];
    for (int i = beg; i < end; ++i) { offsets[i] = run; cursor[i] = run; run += counts[i]; }
    if (tid == 1023) offsets[N] = sums[1023];
}

// ---- scatter edges into CSR slots, one 8B write per edge ----
__global__ void fill_kernel(const int* __restrict__ ei, const float* __restrict__ ew,
                            int* __restrict__ cursor, int2* __restrict__ csr, int E) {
    int e = blockIdx.x * blockDim.x + threadIdx.x;
    if (e >= E) return;
    int p = atomicAdd(cursor + ei[E + e], 1);
    csr[p] = make_int2(ei[e], __float_as_int(ew[e]));
}

// ---- fused layer: gather + (normalize) + [h,g]@W+b + (normalize|tanh) ----
// block = 256 threads = 8 nodes x 32 lanes; lane j owns feature j.
// Gather: chunks of 32 edges; lane j does a clamped (never-OOB) coalesced load of
// edge base+j, OOB lanes get w=0 via cndmask (NO branches). Inner 32-step loop is
// fully unrolled and branch-free so all 32 independent h-row loads can be in
// flight simultaneously.
template <bool LIFT>
__global__ void layer_kernel(const float* __restrict__ h,
                             const int* __restrict__ offsets,
                             const int2* __restrict__ csr,
                             const float* __restrict__ W,  // [64*32] (k, j)
                             const float* __restrict__ b,  // [32]
                             float* __restrict__ out,
                             int N) {
    __shared__ float Ws[64 * R];
    __shared__ float hg[8][64];

    for (int i = threadIdx.x; i < 64 * R; i += blockDim.x) Ws[i] = W[i];

    const int grp  = threadIdx.x >> 5;
    const int j    = threadIdx.x & 31;
    const int node = blockIdx.x * 8 + grp;

    float hv = 0.f, gv = 0.f;
    if (node < N) {
        hv = h[(long long)node * R + j];
        const int beg = offsets[node];
        const int end = offsets[node + 1];
        float a0 = 0.f, a1 = 0.f, a2 = 0.f, a3 = 0.f;
        for (int base = beg; base < end; base += 32) {
            const int e  = base + j;
            const int ee = min(e, end - 1);        // clamped, always in-bounds
            int2 p = csr[ee];
            int   s = p.x;
            float w = (e < end) ? __int_as_float(p.y) : 0.f;  // cndmask, no branch
            #pragma unroll
            for (int k = 0; k < 32; ++k) {
                int   sk = __shfl(s, k, 32);
                float wk = __shfl(w, k, 32);
                float& acc = (k & 2) ? ((k & 1) ? a3 : a2) : ((k & 1) ? a1 : a0);
                acc = fmaf(h[(long long)sk * R + j], wk, acc);
            }
        }
        gv = (a0 + a1) + (a2 + a3);
    }

    if (LIFT) {
        float s = gv * gv;
        #pragma unroll
        for (int o = 16; o >= 1; o >>= 1) s += __shfl_xor(s, o, 32);
        gv = gv / fmaxf(sqrtf(s), EPSN);
    }

    hg[grp][j]      = hv;
    hg[grp][32 + j] = gv;
    __syncthreads();

    float acc = b[j];
    const float* row = hg[grp];
    #pragma unroll
    for (int k = 0; k < 64; ++k) acc = fmaf(row[k], Ws[k * R + j], acc);

    if (LIFT) {
        float s = acc * acc;
        #pragma unroll
        for (int o = 16; o >= 1; o >>= 1) s += __shfl_xor(s, o, 32);
        acc = acc / fmaxf(sqrtf(s), EPSN);
    } else {
        acc = tanhf(acc);
    }

    if (node < N) out[(long long)node * R + j] = acc;
}

extern "C" void kernel_launch(void* const* d_in, const int* in_sizes, int n_in,
                              void* d_out, int out_size, void* d_ws, size_t ws_size,
                              hipStream_t stream) {
    const float* x      = (const float*)d_in[0];
    const int*   ei     = (const int*)d_in[1];
    const float* ew     = (const float*)d_in[2];
    const float* lift_W = (const float*)d_in[3];
    const float* lift_b = (const float*)d_in[4];
    const float* proj_W = (const float*)d_in[5];
    const float* proj_b = (const float*)d_in[6];

    const int N = in_sizes[0] / R;
    const int E = in_sizes[2];

    // workspace layout
    float* h0      = (float*)d_ws;
    float* h1      = h0 + (size_t)N * R;
    int*   counts  = (int*)(h1 + (size_t)N * R);
    int*   offsets = counts + N;
    int*   cursor  = offsets + N + 1;
    int2*  csr     = (int2*)(cursor + N + 1);   // +1 pad for alignment

    // ---- CSR build (once, reused by all 12 layers) ----
    hipMemsetAsync(counts, 0, (size_t)N * sizeof(int), stream);
    count_kernel<<<(E + 255) / 256, 256, 0, stream>>>(ei, counts, E);
    scan_kernel<<<1, 1024, 0, stream>>>(counts, offsets, cursor, N);
    fill_kernel<<<(E + 255) / 256, 256, 0, stream>>>(ei, ew, cursor, csr, E);

    // ---- 12 fused layers ----
    const float* cur = x;
    float* buf[2] = {h0, h1};
    const int node_blocks = (N + 7) / 8;

    for (int l = 0; l < 12; ++l) {
        const bool lift = (l < 8);
        const float* W = lift ? (lift_W + (size_t)l * 64 * R) : (proj_W + (size_t)(l - 8) * 64 * R);
        const float* b = lift ? (lift_b + (size_t)l * R)      : (proj_b + (size_t)(l - 8) * R);
        float* dst = (l == 11) ? (float*)d_out : buf[l & 1];
        if (lift)
            layer_kernel<true ><<<node_blocks, 256, 0, stream>>>(cur, offsets, csr, W, b, dst, N);
        else
            layer_kernel<false><<<node_blocks, 256, 0, stream>>>(cur, offsets, csr, W, b, dst, N);
        cur = dst;
    }
}

// Round 5
// 596.794 us; speedup vs baseline: 1.4728x; 1.4356x over previous
//
#include <hip/hip_runtime.h>
#include <math.h>

// LiftProjectNetwork: binned CSR build + fused gather/MLP layers.
// N=50000, E=1600000, r=32.  Requires N <= 65536 (src packed in 16 bits).
//
// CSR build (once per call, reused by 12 layers):
//   A) bin_scatter: partition edges into nb = ceil(N/256) dst-bins.
//      Per-block LDS histogram -> one global atomicAdd per (block,bin) to
//      reserve a dense run -> packed (src | dstlocal<<16, w) written in
//      ~dense runs (kills the 64B-line-per-edge scattered-write cost).
//   B) bin_scan: exclusive scan of bin counts -> bin bases in csr.
//   C) csr_build: one block per bin; LDS count + scan + scatter within the
//      bin's contiguous (L2-resident) csr region; also emits offsets[].
// Layers: 8 nodes/block, 32 lanes/node (lane j = feature j).
//   gather: 32-edge chunks staged in LDS, broadcast ds_read_b64 per edge,
//   branch-free; MLP: transposed W in padded LDS, float4 reads.

#define R 32
#define EPSN 1e-12f
#define BINW 256     // nodes per bin
#define CAP  9216    // bin capacity (avg ~8163, sigma ~90 -> +12 sigma)
#define EPB  8192    // edges per bin_scatter block

// ---- A: partition edges into dst-bins with dense writes ----
__launch_bounds__(256)
__global__ void bin_scatter_kernel(const int* __restrict__ ei, const float* __restrict__ ew,
                                   int* __restrict__ gcur, int2* __restrict__ binned,
                                   int E, int nb) {
    __shared__ int lhist[BINW];
    __shared__ int lbase[BINW];
    __shared__ int lcur[BINW];
    for (int i = threadIdx.x; i < nb; i += 256) { lhist[i] = 0; lcur[i] = 0; }
    __syncthreads();
    const int e0 = blockIdx.x * EPB;
    const int e1 = min(e0 + EPB, E);
    for (int e = e0 + threadIdx.x; e < e1; e += 256)
        atomicAdd(&lhist[ei[E + e] >> 8], 1);
    __syncthreads();
    for (int i = threadIdx.x; i < nb; i += 256)
        lbase[i] = atomicAdd(&gcur[i], lhist[i]);
    __syncthreads();
    for (int e = e0 + threadIdx.x; e < e1; e += 256) {
        const int d = ei[E + e];
        const int s = ei[e];
        const int bin = d >> 8, dl = d & 255;
        const int slot = lbase[bin] + atomicAdd(&lcur[bin], 1);
        if (slot < CAP)
            binned[(size_t)bin * CAP + slot] = make_int2(s | (dl << 16), __float_as_int(ew[e]));
    }
}

// ---- B: exclusive scan of bin counts (nb <= 256) ----
__global__ void bin_scan_kernel(const int* __restrict__ bincnt, int* __restrict__ binoff, int nb) {
    __shared__ int s[256];
    const int tid = threadIdx.x;
    const int v0 = (tid < nb) ? bincnt[tid] : 0;
    s[tid] = v0;
    __syncthreads();
    for (int off = 1; off < 256; off <<= 1) {
        int v = (tid >= off) ? s[tid - off] : 0;
        __syncthreads();
        s[tid] += v;
        __syncthreads();
    }
    if (tid < nb) binoff[tid] = s[tid] - v0;   // exclusive
}

// ---- C: per-bin CSR build + offsets ----
__launch_bounds__(256)
__global__ void csr_build_kernel(const int2* __restrict__ binned, const int* __restrict__ bincnt,
                                 const int* __restrict__ binoff,
                                 int* __restrict__ offsets, int2* __restrict__ csr,
                                 int N, int E, int nb) {
    __shared__ int cnt[BINW];
    __shared__ int sc[BINW];
    __shared__ int excl[BINW];
    __shared__ int cur[BINW];
    const int b = blockIdx.x;
    const int tid = threadIdx.x;
    cnt[tid] = 0; cur[tid] = 0;
    __syncthreads();
    const int2* src = binned + (size_t)b * CAP;
    const int n = bincnt[b];
    const int base = binoff[b];
    for (int i = tid; i < n; i += 256)
        atomicAdd(&cnt[((unsigned)src[i].x) >> 16], 1);
    __syncthreads();
    sc[tid] = cnt[tid];
    __syncthreads();
    for (int off = 1; off < 256; off <<= 1) {
        int v = (tid >= off) ? sc[tid - off] : 0;
        __syncthreads();
        sc[tid] += v;
        __syncthreads();
    }
    excl[tid] = sc[tid] - cnt[tid];
    const int node = b * BINW + tid;
    if (node < N) offsets[node] = base + excl[tid];
    if (b == nb - 1 && tid == 0) offsets[N] = E;
    __syncthreads();
    for (int i = tid; i < n; i += 256) {
        const int2 p = src[i];
        const unsigned key = (unsigned)p.x;
        const int dl = key >> 16;
        const int s  = key & 0xffff;
        const int slot = base + excl[dl] + atomicAdd(&cur[dl], 1);
        csr[slot] = make_int2(s, p.y);
    }
}

// ---- fused layer: gather + (normalize) + [h,g]@W+b + (normalize|tanh) ----
template <bool LIFT>
__launch_bounds__(256)
__global__ void layer_kernel(const float* __restrict__ h,
                             const int* __restrict__ offsets,
                             const int2* __restrict__ csr,
                             const float* __restrict__ W,  // [64*32] (k, j)
                             const float* __restrict__ b,  // [32]
                             float* __restrict__ out,
                             int N) {
    __shared__ float WsT[32][68];   // WsT[j][k] = W[k][j]; pad 68 (272B rows, 16B aligned)
    __shared__ float hg[8][64];
    __shared__ int2  es[8][32];

    for (int i = threadIdx.x; i < 64 * 32; i += 256) WsT[i & 31][i >> 5] = W[i];

    const int grp  = threadIdx.x >> 5;
    const int j    = threadIdx.x & 31;
    const int node = blockIdx.x * 8 + grp;

    if (node < N) {
        const float hv = h[(long long)node * R + j];
        const int beg = offsets[node];
        const int end = offsets[node + 1];
        float a0 = 0.f, a1 = 0.f, a2 = 0.f, a3 = 0.f;
        for (int base = beg; base < end; base += 32) {
            const int e = base + j;
            int2 p = csr[min(e, end - 1)];           // clamped, in-bounds
            if (e >= end) p.y = 0;                    // w=0, no branch
            es[grp][j] = p;                           // same-wave produce/consume, no barrier
            #pragma unroll
            for (int k = 0; k < 32; ++k) {
                const int2 q = es[grp][k];            // broadcast LDS read
                float& acc = (k & 2) ? ((k & 1) ? a3 : a2) : ((k & 1) ? a1 : a0);
                acc = fmaf(h[(long long)q.x * R + j], __int_as_float(q.y), acc);
            }
        }
        float gv = (a0 + a1) + (a2 + a3);
        if (LIFT) {
            float s = gv * gv;
            #pragma unroll
            for (int o = 16; o >= 1; o >>= 1) s += __shfl_xor(s, o, 32);
            gv = gv / fmaxf(sqrtf(s), EPSN);
        }
        hg[grp][j]      = hv;
        hg[grp][32 + j] = gv;
    }
    __syncthreads();

    float acc = b[j];
    #pragma unroll
    for (int kb = 0; kb < 16; ++kb) {
        const float4 r  = *reinterpret_cast<const float4*>(&hg[grp][kb * 4]);   // broadcast
        const float4 wv = *reinterpret_cast<const float4*>(&WsT[j][kb * 4]);
        acc = fmaf(r.x, wv.x, acc);
        acc = fmaf(r.y, wv.y, acc);
        acc = fmaf(r.z, wv.z, acc);
        acc = fmaf(r.w, wv.w, acc);
    }

    if (LIFT) {
        float s = acc * acc;
        #pragma unroll
        for (int o = 16; o >= 1; o >>= 1) s += __shfl_xor(s, o, 32);
        acc = acc / fmaxf(sqrtf(s), EPSN);
    } else {
        acc = tanhf(acc);
    }

    if (node < N) out[(long long)node * R + j] = acc;
}

extern "C" void kernel_launch(void* const* d_in, const int* in_sizes, int n_in,
                              void* d_out, int out_size, void* d_ws, size_t ws_size,
                              hipStream_t stream) {
    const float* x      = (const float*)d_in[0];
    const int*   ei     = (const int*)d_in[1];
    const float* ew     = (const float*)d_in[2];
    const float* lift_W = (const float*)d_in[3];
    const float* lift_b = (const float*)d_in[4];
    const float* proj_W = (const float*)d_in[5];
    const float* proj_b = (const float*)d_in[6];

    const int N = in_sizes[0] / R;
    const int E = in_sizes[2];
    const int nb = (N + BINW - 1) / BINW;

    // workspace layout (d_out doubles as the odd-layer ping-pong buffer)
    float* h0      = (float*)d_ws;                       // N*R
    int*   offsets = (int*)(h0 + (size_t)N * R);         // N+1
    int*   gcur    = offsets + N + 1;                    // 256
    int*   binoff  = gcur + 256;                         // 256
    uintptr_t p    = (uintptr_t)(binoff + 256);
    p = (p + 15) & ~(uintptr_t)15;
    int2*  binned  = (int2*)p;                           // nb*CAP
    int2*  csr     = binned + (size_t)nb * CAP;          // E

    // ---- CSR build ----
    hipMemsetAsync(gcur, 0, 256 * sizeof(int), stream);
    bin_scatter_kernel<<<(E + EPB - 1) / EPB, 256, 0, stream>>>(ei, ew, gcur, binned, E, nb);
    bin_scan_kernel<<<1, 256, 0, stream>>>(gcur, binoff, nb);
    csr_build_kernel<<<nb, 256, 0, stream>>>(binned, gcur, binoff, offsets, csr, N, E, nb);

    // ---- 12 fused layers (ping-pong h0 <-> d_out) ----
    const float* cur = x;
    float* fout = (float*)d_out;
    const int node_blocks = (N + 7) / 8;

    for (int l = 0; l < 12; ++l) {
        const bool lift = (l < 8);
        const float* W = lift ? (lift_W + (size_t)l * 64 * R) : (proj_W + (size_t)(l - 8) * 64 * R);
        const float* b = lift ? (lift_b + (size_t)l * R)      : (proj_b + (size_t)(l - 8) * R);
        float* dst = (l & 1) ? fout : h0;   // layer 11 (odd) -> d_out
        if (lift)
            layer_kernel<true ><<<node_blocks, 256, 0, stream>>>(cur, offsets, csr, W, b, dst, N);
        else
            layer_kernel<false><<<node_blocks, 256, 0, stream>>>(cur, offsets, csr, W, b, dst, N);
        cur = dst;
    }
}

// Round 6
// 538.925 us; speedup vs baseline: 1.6309x; 1.1074x over previous
//
#include <hip/hip_runtime.h>
#include <math.h>

// LiftProjectNetwork: binned CSR build + fused gather/MLP layers.
// N=50000, E=1600000, r=32.  Requires N <= 65536 (src packed in 16 bits in bins).
//
// CSR build (once per call, reused by 12 layers):
//   A) bin_scatter: partition edges into nb = ceil(N/256) dst-bins (dense writes).
//   B) bin_scan: exclusive scan of bin counts.
//   C) csr_build: per-bin LDS count/scan/scatter; csr stores (src*128, w) so the
//      layer gather does single 32-bit-offset addressing.
// Layers: 8 nodes/block, 32 lanes/node. Gather is 4-edges x 8-lanes wide:
//   each lane float4-loads 16B of its edge's h-row; (src,w) read straight from
//   csr (4 consecutive int2 per group, L1-served); cross-lane reduce via
//   shfl_xor(8,16). VGPR capped at 64 for 32 waves/CU occupancy.

#define R 32
#define EPSN 1e-12f
#define BINW 256     // nodes per bin
#define CAP  9216    // bin capacity (avg ~8192, sigma ~90)
#define EPB  8192    // edges per bin_scatter block

// ---- A: partition edges into dst-bins with dense writes ----
__launch_bounds__(256)
__global__ void bin_scatter_kernel(const int* __restrict__ ei, const float* __restrict__ ew,
                                   int* __restrict__ gcur, int2* __restrict__ binned,
                                   int E, int nb) {
    __shared__ int lhist[BINW];
    __shared__ int lbase[BINW];
    __shared__ int lcur[BINW];
    for (int i = threadIdx.x; i < nb; i += 256) { lhist[i] = 0; lcur[i] = 0; }
    __syncthreads();
    const int e0 = blockIdx.x * EPB;
    const int e1 = min(e0 + EPB, E);
    for (int e = e0 + threadIdx.x; e < e1; e += 256)
        atomicAdd(&lhist[ei[E + e] >> 8], 1);
    __syncthreads();
    for (int i = threadIdx.x; i < nb; i += 256)
        lbase[i] = atomicAdd(&gcur[i], lhist[i]);
    __syncthreads();
    for (int e = e0 + threadIdx.x; e < e1; e += 256) {
        const int d = ei[E + e];
        const int s = ei[e];
        const int bin = d >> 8, dl = d & 255;
        const int slot = lbase[bin] + atomicAdd(&lcur[bin], 1);
        if (slot < CAP)
            binned[(size_t)bin * CAP + slot] = make_int2(s | (dl << 16), __float_as_int(ew[e]));
    }
}

// ---- B: exclusive scan of bin counts (nb <= 256) ----
__global__ void bin_scan_kernel(const int* __restrict__ bincnt, int* __restrict__ binoff, int nb) {
    __shared__ int s[256];
    const int tid = threadIdx.x;
    const int v0 = (tid < nb) ? bincnt[tid] : 0;
    s[tid] = v0;
    __syncthreads();
    for (int off = 1; off < 256; off <<= 1) {
        int v = (tid >= off) ? s[tid - off] : 0;
        __syncthreads();
        s[tid] += v;
        __syncthreads();
    }
    if (tid < nb) binoff[tid] = s[tid] - v0;   // exclusive
}

// ---- C: per-bin CSR build + offsets; csr.x = src byte offset (src*128) ----
__launch_bounds__(256)
__global__ void csr_build_kernel(const int2* __restrict__ binned, const int* __restrict__ bincnt,
                                 const int* __restrict__ binoff,
                                 int* __restrict__ offsets, int2* __restrict__ csr,
                                 int N, int E, int nb) {
    __shared__ int cnt[BINW];
    __shared__ int sc[BINW];
    __shared__ int excl[BINW];
    __shared__ int cur[BINW];
    const int b = blockIdx.x;
    const int tid = threadIdx.x;
    cnt[tid] = 0; cur[tid] = 0;
    __syncthreads();
    const int2* src = binned + (size_t)b * CAP;
    const int n = bincnt[b];
    const int base = binoff[b];
    for (int i = tid; i < n; i += 256)
        atomicAdd(&cnt[((unsigned)src[i].x) >> 16], 1);
    __syncthreads();
    sc[tid] = cnt[tid];
    __syncthreads();
    for (int off = 1; off < 256; off <<= 1) {
        int v = (tid >= off) ? sc[tid - off] : 0;
        __syncthreads();
        sc[tid] += v;
        __syncthreads();
    }
    excl[tid] = sc[tid] - cnt[tid];
    const int node = b * BINW + tid;
    if (node < N) offsets[node] = base + excl[tid];
    if (b == nb - 1 && tid == 0) offsets[N] = E;
    __syncthreads();
    for (int i = tid; i < n; i += 256) {
        const int2 p = src[i];
        const unsigned key = (unsigned)p.x;
        const int dl = key >> 16;
        const int s  = key & 0xffff;
        const int slot = base + excl[dl] + atomicAdd(&cur[dl], 1);
        csr[slot] = make_int2(s << 7, p.y);   // byte offset of h-row
    }
}

// ---- fused layer: gather + (normalize) + [h,g]@W+b + (normalize|tanh) ----
// 8 nodes/block; per node 32 lanes = 4 edges x 8 lanes(float4).
template <bool LIFT>
__launch_bounds__(256, 8)   // cap VGPRs at 64 -> 32 waves/CU
__global__ void layer_kernel(const float* __restrict__ h,
                             const int* __restrict__ offsets,
                             const int2* __restrict__ csr,
                             const float* __restrict__ W,  // [64*32] (k, j)
                             const float* __restrict__ b,  // [32]
                             float* __restrict__ out,
                             int N) {
    __shared__ float WsT[32][68];   // WsT[j][k] = W[k][j]
    __shared__ float hg[8][64];

    for (int i = threadIdx.x; i < 64 * 32; i += 256) WsT[i & 31][i >> 5] = W[i];
    __syncthreads();    // only WsT needs block-wide visibility; hg is same-wave

    const int grp   = threadIdx.x >> 5;
    const int j     = threadIdx.x & 31;
    const int lane8 = j >> 3;            // edge slot within quad
    const unsigned fo = (unsigned)(j & 7) * 16u;   // byte offset of feature quad
    const int node  = blockIdx.x * 8 + grp;
    const char* hb  = (const char*)h;

    // stage h row: lanes 0..7 cover the 128B row with float4s
    if (node < N && j < 8)
        *reinterpret_cast<float4*>(&hg[grp][j * 4]) =
            *reinterpret_cast<const float4*>(hb + (size_t)node * 128 + (size_t)j * 16);

    float4 a0 = make_float4(0.f, 0.f, 0.f, 0.f);
    float4 a1 = make_float4(0.f, 0.f, 0.f, 0.f);
    if (node < N) {
        const int beg = offsets[node];
        const int end = offsets[node + 1];
        for (int base = beg; base < end; base += 32) {
            #pragma unroll
            for (int qs = 0; qs < 8; ++qs) {
                const int eq = base + qs * 4 + lane8;
                const int2 q = csr[min(eq, end - 1)];
                const float w = (eq < end) ? __int_as_float(q.y) : 0.f;
                const float4 hv = *reinterpret_cast<const float4*>(hb + (unsigned)q.x + fo);
                float4& ac = (qs & 1) ? a1 : a0;
                ac.x = fmaf(hv.x, w, ac.x);
                ac.y = fmaf(hv.y, w, ac.y);
                ac.z = fmaf(hv.z, w, ac.z);
                ac.w = fmaf(hv.w, w, ac.w);
            }
        }
    }
    float4 g4 = make_float4(a0.x + a1.x, a0.y + a1.y, a0.z + a1.z, a0.w + a1.w);
    #pragma unroll
    for (int m = 8; m <= 16; m <<= 1) {
        g4.x += __shfl_xor(g4.x, m, 32);
        g4.y += __shfl_xor(g4.y, m, 32);
        g4.z += __shfl_xor(g4.z, m, 32);
        g4.w += __shfl_xor(g4.w, m, 32);
    }

    if (LIFT) {
        float ss = g4.x * g4.x + g4.y * g4.y + g4.z * g4.z + g4.w * g4.w;
        ss += __shfl_xor(ss, 1, 32);
        ss += __shfl_xor(ss, 2, 32);
        ss += __shfl_xor(ss, 4, 32);
        const float sc = 1.f / fmaxf(sqrtf(ss), EPSN);
        g4.x *= sc; g4.y *= sc; g4.z *= sc; g4.w *= sc;
    }
    if (node < N && j < 8)
        *reinterpret_cast<float4*>(&hg[grp][32 + j * 4]) = g4;   // lane j holds quad j

    // MLP: lane j computes output feature j  (hg is same-wave: no barrier)
    float acc0 = b[j], acc1 = 0.f;
    #pragma unroll
    for (int kb = 0; kb < 16; ++kb) {
        const float4 r  = *reinterpret_cast<const float4*>(&hg[grp][kb * 4]);
        const float4 wv = *reinterpret_cast<const float4*>(&WsT[j][kb * 4]);
        float& acc = (kb & 1) ? acc1 : acc0;
        acc = fmaf(r.x, wv.x, acc);
        acc = fmaf(r.y, wv.y, acc);
        acc = fmaf(r.z, wv.z, acc);
        acc = fmaf(r.w, wv.w, acc);
    }
    float acc = acc0 + acc1;

    if (LIFT) {
        float s = acc * acc;
        #pragma unroll
        for (int o = 16; o >= 1; o >>= 1) s += __shfl_xor(s, o, 32);
        acc = acc / fmaxf(sqrtf(s), EPSN);
    } else {
        acc = tanhf(acc);
    }

    if (node < N) out[(long long)node * R + j] = acc;
}

extern "C" void kernel_launch(void* const* d_in, const int* in_sizes, int n_in,
                              void* d_out, int out_size, void* d_ws, size_t ws_size,
                              hipStream_t stream) {
    const float* x      = (const float*)d_in[0];
    const int*   ei     = (const int*)d_in[1];
    const float* ew     = (const float*)d_in[2];
    const float* lift_W = (const float*)d_in[3];
    const float* lift_b = (const float*)d_in[4];
    const float* proj_W = (const float*)d_in[5];
    const float* proj_b = (const float*)d_in[6];

    const int N = in_sizes[0] / R;
    const int E = in_sizes[2];
    const int nb = (N + BINW - 1) / BINW;

    // workspace layout (d_out doubles as the odd-layer ping-pong buffer)
    float* h0      = (float*)d_ws;                       // N*R
    int*   offsets = (int*)(h0 + (size_t)N * R);         // N+1
    int*   gcur    = offsets + N + 1;                    // 256
    int*   binoff  = gcur + 256;                         // 256
    uintptr_t p    = (uintptr_t)(binoff + 256);
    p = (p + 15) & ~(uintptr_t)15;
    int2*  binned  = (int2*)p;                           // nb*CAP
    int2*  csr     = binned + (size_t)nb * CAP;          // E

    // ---- CSR build ----
    hipMemsetAsync(gcur, 0, 256 * sizeof(int), stream);
    bin_scatter_kernel<<<(E + EPB - 1) / EPB, 256, 0, stream>>>(ei, ew, gcur, binned, E, nb);
    bin_scan_kernel<<<1, 256, 0, stream>>>(gcur, binoff, nb);
    csr_build_kernel<<<nb, 256, 0, stream>>>(binned, gcur, binoff, offsets, csr, N, E, nb);

    // ---- 12 fused layers (ping-pong h0 <-> d_out) ----
    const float* cur = x;
    float* fout = (float*)d_out;
    const int node_blocks = (N + 7) / 8;

    for (int l = 0; l < 12; ++l) {
        const bool lift = (l < 8);
        const float* W = lift ? (lift_W + (size_t)l * 64 * R) : (proj_W + (size_t)(l - 8) * 64 * R);
        const float* b = lift ? (lift_b + (size_t)l * R)      : (proj_b + (size_t)(l - 8) * R);
        float* dst = (l & 1) ? fout : h0;   // layer 11 (odd) -> d_out
        if (lift)
            layer_kernel<true ><<<node_blocks, 256, 0, stream>>>(cur, offsets, csr, W, b, dst, N);
        else
            layer_kernel<false><<<node_blocks, 256, 0, stream>>>(cur, offsets, csr, W, b, dst, N);
        cur = dst;
    }
}